// Round 15
// baseline (734.789 us; speedup 1.0000x reference)
//
#include <hip/hip_runtime.h>
#include <hip/hip_bf16.h>
#include <hip/hip_cooperative_groups.h>

namespace cg = cooperative_groups;

#define N_NODES 50000
#define N_EDGES 800000
#define BSHIFT  5
#define BUCKS   1563           // ceil(50000 / 32)
#define NPAD    50016          // BUCKS * 32
#define BSTRIDE 1024           // slots per bucket (mean 512, ~22 sigma headroom)
#define BCAP    1024
#define IN_DIM  100
#define HID     128
#define BN_EPS  1e-5f
#define NSLICE  32             // stats atomic slices

#define COOP_BLKS 782          // coop grid: 2 buckets per block, well under capacity
#define SC_BLKS 98             // scatter blocks: ceil(800000/8192)
#define CAST_ELEMS (NPAD * 128 + 4 * 16384)
#define CAST_BLKS ((CAST_ELEMS + 4095) / 4096)

typedef unsigned int uint;
typedef unsigned short u16;
typedef __attribute__((ext_vector_type(8))) unsigned short us8;
typedef __attribute__((ext_vector_type(8))) short s8;       // bf16 MFMA frag
typedef __attribute__((ext_vector_type(16))) float f16v;    // 32x32 accumulator

__device__ __forceinline__ u16 f2bf(float f) {
    uint u = __builtin_bit_cast(uint, f);
    uint r = (u + 0x7FFFu + ((u >> 16) & 1u)) >> 16;   // RNE
    return (u16)r;
}
__device__ __forceinline__ uint pack2(float a, float b) {
    return (uint)f2bf(a) | ((uint)f2bf(b) << 16);
}
__device__ __forceinline__ float bflo(uint p) { return __builtin_bit_cast(float, p << 16); }
__device__ __forceinline__ float bfhi(uint p) { return __builtin_bit_cast(float, p & 0xFFFF0000u); }

// ---------------------------------------------------------------------------
// Fat preprocessing kernel: blocks [0,SC_BLKS) scatter edges into buckets;
// blocks [SC_BLKS, ...) cast x->bf16 padded + weights->bf16^T.
// ---------------------------------------------------------------------------
__global__ __launch_bounds__(1024) void scatter_cast(
    const int* __restrict__ src, const int* __restrict__ dst,
    int* __restrict__ bcursor, uint* __restrict__ ebuf,
    const float* __restrict__ x,
    const float* __restrict__ W_l0, const float* __restrict__ W_r0,
    const float* __restrict__ W_l1, const float* __restrict__ W_r1,
    u16* __restrict__ xb, u16* __restrict__ Wt) {
    __shared__ int h[BUCKS];
    __shared__ int gb[BUCKS];
    int t = threadIdx.x;

    if (blockIdx.x >= SC_BLKS) {
        int base = (blockIdx.x - SC_BLKS) * 4096 + t;
        #pragma unroll
        for (int r = 0; r < 4; ++r) {
            int idx = base + r * 1024;
            if (idx < NPAD * 128) {
                int row = idx >> 7, k = idx & 127;
                float v = (row < N_NODES && k < IN_DIM) ? x[row * IN_DIM + k] : 0.f;
                xb[idx] = f2bf(v);
            } else if (idx < CAST_ELEMS) {
                int i2 = idx - NPAD * 128;
                int w = i2 >> 14, i3 = i2 & 16383;
                const float* s = (w == 0) ? W_l0 : (w == 1) ? W_r0 : (w == 2) ? W_l1 : W_r1;
                int Ks = (w < 2) ? IN_DIM : HID;
                int n = i3 >> 7, k = i3 & 127;
                float v = (k < Ks) ? s[k * 128 + n] : 0.f;
                Wt[i2] = f2bf(v);
            }
        }
        return;
    }

    for (int i = t; i < BUCKS; i += 1024) h[i] = 0;
    __syncthreads();
    int base = blockIdx.x * 8192;
    int myb[8]; uint myv[8];
    #pragma unroll
    for (int r = 0; r < 8; ++r) {
        int e = base + r * 1024 + t;
        int b = -1; uint val = 0;
        if (e < N_EDGES) {
            int d = dst[e];
            b = d >> BSHIFT;
            val = (uint)src[e] | ((uint)(d & 31) << 16);
            atomicAdd(&h[b], 1);
        }
        myb[r] = b; myv[r] = val;
    }
    __syncthreads();
    for (int i = t; i < BUCKS; i += 1024) {
        int c = h[i];
        gb[i] = c ? (i * BSTRIDE + atomicAdd(&bcursor[i], c)) : 0;
        h[i] = 0;
    }
    __syncthreads();
    #pragma unroll
    for (int r = 0; r < 8; ++r) {
        int b = myb[r];
        if (b >= 0) {
            int pos = gb[b] + atomicAdd(&h[b], 1);
            ebuf[pos] = myv[r];
        }
    }
}

// ---------------------------------------------------------------------------
// Per-bucket work (round-11 verified): LDS CSR -> quad-owns-node gather-mean
// -> 32x32x16 MFMA (B/root-A direct from global) -> store + LDS stat accum.
// ---------------------------------------------------------------------------
template <int WRITE_BF16>
__device__ __forceinline__ void bucket_pass(
    int b, int t,
    const uint* __restrict__ ebuf, const int* __restrict__ bcursor,
    const u16* __restrict__ X,
    const u16* __restrict__ WtL, const u16* __restrict__ WtR,
    const float* __restrict__ bias,
    float* __restrict__ outf, u16* __restrict__ outb,
    u16 (*Aagg)[136], uint* eL, u16* srcL,
    int* cnt, int* ro, int* cur, float* s1L, float* s2L) {
    int row0 = b * 32;
    int wave = t >> 6, lane = t & 63;
    int quad = lane >> 4, sub = lane & 15;

    // ---- bucket-local CSR in LDS
    int n = bcursor[b];
    if (n > BCAP) n = BCAP;
    if (t < 32) cnt[t] = 0;
    __syncthreads();
    for (int i = t; i < n; i += 256) {
        uint p = ebuf[b * BSTRIDE + i];
        eL[i] = p;
        atomicAdd(&cnt[p >> 16], 1);
    }
    __syncthreads();
    if (t < 32) {
        int v = cnt[t];
        int s = v;
        #pragma unroll
        for (int off = 1; off < 32; off <<= 1) {
            int u = __shfl_up(s, off, 64);
            if (t >= off) s += u;
        }
        ro[t] = s - v;
        cur[t] = s - v;
        if (t == 31) ro[32] = s;
    }
    __syncthreads();
    for (int i = t; i < n; i += 256) {
        uint p = eL[i];
        int pos = atomicAdd(&cur[p >> 16], 1);
        srcL[pos] = (u16)(p & 0xFFFFu);
    }
    __syncthreads();

    // ---- gather-mean: each of 16 quads owns 2 nodes
    int nl0 = (wave * 4 + quad) * 2;
    #pragma unroll
    for (int g = 0; g < 2; ++g) {
        int nl = nl0 + g;
        int rb = ro[nl], re = ro[nl + 1];
        float a0 = 0.f, a1 = 0.f, a2 = 0.f, a3 = 0.f;
        float a4 = 0.f, a5 = 0.f, a6 = 0.f, a7 = 0.f;
        int e = rb;
        for (; e + 4 <= re; e += 4) {
            int s0 = srcL[e], s1 = srcL[e + 1], s2 = srcL[e + 2], s3 = srcL[e + 3];
            uint4 v0 = ((const uint4*)(X + (size_t)s0 * 128))[sub];
            uint4 v1 = ((const uint4*)(X + (size_t)s1 * 128))[sub];
            uint4 v2 = ((const uint4*)(X + (size_t)s2 * 128))[sub];
            uint4 v3 = ((const uint4*)(X + (size_t)s3 * 128))[sub];
            a0 += (bflo(v0.x) + bflo(v1.x)) + (bflo(v2.x) + bflo(v3.x));
            a1 += (bfhi(v0.x) + bfhi(v1.x)) + (bfhi(v2.x) + bfhi(v3.x));
            a2 += (bflo(v0.y) + bflo(v1.y)) + (bflo(v2.y) + bflo(v3.y));
            a3 += (bfhi(v0.y) + bfhi(v1.y)) + (bfhi(v2.y) + bfhi(v3.y));
            a4 += (bflo(v0.z) + bflo(v1.z)) + (bflo(v2.z) + bflo(v3.z));
            a5 += (bfhi(v0.z) + bfhi(v1.z)) + (bfhi(v2.z) + bfhi(v3.z));
            a6 += (bflo(v0.w) + bflo(v1.w)) + (bflo(v2.w) + bflo(v3.w));
            a7 += (bfhi(v0.w) + bfhi(v1.w)) + (bfhi(v2.w) + bfhi(v3.w));
        }
        for (; e < re; ++e) {
            uint4 v0 = ((const uint4*)(X + (size_t)srcL[e] * 128))[sub];
            a0 += bflo(v0.x); a1 += bfhi(v0.x);
            a2 += bflo(v0.y); a3 += bfhi(v0.y);
            a4 += bflo(v0.z); a5 += bfhi(v0.z);
            a6 += bflo(v0.w); a7 += bfhi(v0.w);
        }
        float inv = 1.0f / fmaxf((float)(re - rb), 1.0f);
        uint4 o;
        o.x = pack2(a0 * inv, a1 * inv);
        o.y = pack2(a2 * inv, a3 * inv);
        o.z = pack2(a4 * inv, a5 * inv);
        o.w = pack2(a6 * inv, a7 * inv);
        *(uint4*)&Aagg[nl][sub * 8] = o;
    }
    __syncthreads();   // Aagg complete

    // ---- dual GEMM: wave -> rows 0..31 of tile, cols cn..cn+31
    int m31 = lane & 31;
    int kh  = lane >> 5;
    int cn = wave * 32;
    f16v acc = (f16v)0.f;

    {
        s8 a_nxt = *(const s8*)&Aagg[m31][kh * 8];
        s8 b_nxt = *(const s8*)(WtL + (cn + m31) * 128 + kh * 8);
        #pragma unroll
        for (int ks = 0; ks < 8; ++ks) {
            s8 a_cur = a_nxt, b_cur = b_nxt;
            if (ks < 7) {
                a_nxt = *(const s8*)&Aagg[m31][(ks + 1) * 16 + kh * 8];
                b_nxt = *(const s8*)(WtL + (cn + m31) * 128 + (ks + 1) * 16 + kh * 8);
            }
            acc = __builtin_amdgcn_mfma_f32_32x32x16_bf16(a_cur, b_cur, acc, 0, 0, 0);
        }
    }
    {
        const u16* xrow = X + (size_t)(row0 + m31) * 128;
        s8 a_nxt = *(const s8*)(xrow + kh * 8);
        s8 b_nxt = *(const s8*)(WtR + (cn + m31) * 128 + kh * 8);
        #pragma unroll
        for (int ks = 0; ks < 8; ++ks) {
            s8 a_cur = a_nxt, b_cur = b_nxt;
            if (ks < 7) {
                a_nxt = *(const s8*)(xrow + (ks + 1) * 16 + kh * 8);
                b_nxt = *(const s8*)(WtR + (cn + m31) * 128 + (ks + 1) * 16 + kh * 8);
            }
            acc = __builtin_amdgcn_mfma_f32_32x32x16_bf16(a_cur, b_cur, acc, 0, 0, 0);
        }
    }

    // ---- epilogue: store + BN partial stats into LDS
    // C/D 32x32: col=lane&31, row=(reg&3)+8*(reg>>2)+4*(lane>>5)  [m74/m101]
    {
        int col = cn + m31;
        float bv = bias[col];
        float s1 = 0.f, s2 = 0.f;
        #pragma unroll
        for (int reg = 0; reg < 16; ++reg) {
            int rowin = (reg & 3) + 8 * (reg >> 2) + 4 * kh;
            int row = row0 + rowin;
            if (row < N_NODES) {
                float v = acc[reg] + bv;
                if (WRITE_BF16)
                    outb[(size_t)row * 128 + col] = f2bf(v);
                else
                    outf[(size_t)row * 128 + col] = v;
                s1 += v;
                s2 = fmaf(v, v, s2);
            }
        }
        s1 += __shfl_xor(s1, 32, 64);
        s2 += __shfl_xor(s2, 32, 64);
        if (lane < 32) {
            atomicAdd(&s1L[col], s1);
            atomicAdd(&s2L[col], s2);
        }
    }
}

// ---------------------------------------------------------------------------
// Cooperative kernel: both layers + BN, grid-synced. 782 blocks x 256 thr,
// 2 buckets/block. launch_bounds(256,4) -> ample coop capacity.
// ---------------------------------------------------------------------------
__global__ __launch_bounds__(256, 4) void fused_layers(
    const uint* __restrict__ ebuf, const int* __restrict__ bcursor,
    const u16* __restrict__ xb, u16* __restrict__ hb,
    const u16* __restrict__ Wt,
    const float* __restrict__ b_l0, const float* __restrict__ b_l1,
    const float* __restrict__ gamma0, const float* __restrict__ beta0,
    const float* __restrict__ gamma1, const float* __restrict__ beta1,
    float* __restrict__ outp,
    float* __restrict__ gstats0, float* __restrict__ gstats1,
    float inv_n) {
    cg::grid_group grid = cg::this_grid();

    __shared__ u16 Aagg[32][136];
    __shared__ uint eL[BCAP];
    __shared__ u16 srcL[BCAP];
    __shared__ int cnt[32], ro[33], cur[32];
    __shared__ float s1L[128], s2L[128];
    __shared__ float ss[256];

    int t = threadIdx.x;

    #pragma unroll 1
    for (int layer = 0; layer < 2; ++layer) {
        const u16* X = layer ? hb : xb;
        const u16* WtL = Wt + (layer * 2) * 16384;
        const u16* WtR = Wt + (layer * 2 + 1) * 16384;
        const float* bias = layer ? b_l1 : b_l0;
        float* gso = layer ? gstats1 : gstats0;

        if (t < 128) { s1L[t] = 0.f; s2L[t] = 0.f; }

        #pragma unroll 1
        for (int g = 0; g < 2; ++g) {
            int b = blockIdx.x * 2 + g;
            if (b < BUCKS) {
                if (layer == 0)
                    bucket_pass<1>(b, t, ebuf, bcursor, X, WtL, WtR, bias,
                                   nullptr, hb, Aagg, eL, srcL, cnt, ro, cur, s1L, s2L);
                else
                    bucket_pass<0>(b, t, ebuf, bcursor, X, WtL, WtR, bias,
                                   outp, nullptr, Aagg, eL, srcL, cnt, ro, cur, s1L, s2L);
            }
            __syncthreads();
        }

        int slice = blockIdx.x & (NSLICE - 1);
        if (t < 128) {
            atomicAdd(&gso[slice * 256 + t], s1L[t]);
            atomicAdd(&gso[slice * 256 + 128 + t], s2L[t]);
        }
        __threadfence();
        grid.sync();

        // ---- BN finalize (per block) + elementwise phase
        const float* gs  = layer ? gstats1 : gstats0;
        const float* gam = layer ? gamma1 : gamma0;
        const float* bet = layer ? beta1 : beta0;
        if (t < 128) {
            float m = 0.f, q = 0.f;
            #pragma unroll
            for (int s = 0; s < NSLICE; ++s) {
                m += gs[s * 256 + t];
                q += gs[s * 256 + 128 + t];
            }
            float mean = m * inv_n;
            float var = q * inv_n - mean * mean;
            float inv = 1.0f / sqrtf(var + BN_EPS);
            float sc = gam[t] * inv;
            ss[t] = sc;
            ss[128 + t] = bet[t] - mean * sc;
        }
        __syncthreads();

        if (layer == 0) {
            const int totalv = N_NODES * 16;   // uint4s of bf16 hb
            for (int i = blockIdx.x * 256 + t; i < totalv; i += COOP_BLKS * 256) {
                int cg2 = (i & 15) * 8;
                uint4 p = ((const uint4*)hb)[i];
                float4 scA = *(const float4*)&ss[cg2];
                float4 scB = *(const float4*)&ss[cg2 + 4];
                float4 shA = *(const float4*)&ss[128 + cg2];
                float4 shB = *(const float4*)&ss[128 + cg2 + 4];
                float r0 = fmaxf(fmaf(bflo(p.x), scA.x, shA.x), 0.f);
                float r1 = fmaxf(fmaf(bfhi(p.x), scA.y, shA.y), 0.f);
                float r2 = fmaxf(fmaf(bflo(p.y), scA.z, shA.z), 0.f);
                float r3 = fmaxf(fmaf(bfhi(p.y), scA.w, shA.w), 0.f);
                float r4 = fmaxf(fmaf(bflo(p.z), scB.x, shB.x), 0.f);
                float r5 = fmaxf(fmaf(bfhi(p.z), scB.y, shB.y), 0.f);
                float r6 = fmaxf(fmaf(bflo(p.w), scB.z, shB.z), 0.f);
                float r7 = fmaxf(fmaf(bfhi(p.w), scB.w, shB.w), 0.f);
                uint4 o;
                o.x = pack2(r0, r1);
                o.y = pack2(r2, r3);
                o.z = pack2(r4, r5);
                o.w = pack2(r6, r7);
                ((uint4*)hb)[i] = o;
            }
            __threadfence();
            grid.sync();
            __syncthreads();
        } else {
            const int total4 = N_NODES * 32;   // float4s of fp32 out
            for (int i = blockIdx.x * 256 + t; i < total4; i += COOP_BLKS * 256) {
                int cg2 = i & 31;
                float4 v = ((float4*)outp)[i];
                float4 sc = *(const float4*)&ss[cg2 * 4];
                float4 sh = *(const float4*)&ss[128 + cg2 * 4];
                v.x = fmaf(v.x, sc.x, sh.x);
                v.y = fmaf(v.y, sc.y, sh.y);
                v.z = fmaf(v.z, sc.z, sh.z);
                v.w = fmaf(v.w, sc.w, sh.w);
                ((float4*)outp)[i] = v;
            }
        }
    }
}

// ---------------------------------------------------------------------------
// Fallback (non-cooperative) path — round-11-proven kernels
// ---------------------------------------------------------------------------
template <int WRITE_BF16>
__global__ __launch_bounds__(256) void agg_gemm_nc(
    const uint* __restrict__ ebuf, const int* __restrict__ bcursor,
    const u16* __restrict__ X,
    const u16* __restrict__ WtL, const u16* __restrict__ WtR,
    const float* __restrict__ bias,
    float* __restrict__ outf, u16* __restrict__ outb,
    float* __restrict__ gstats) {
    __shared__ u16 Aagg[32][136];
    __shared__ uint eL[BCAP];
    __shared__ u16 srcL[BCAP];
    __shared__ int cnt[32], ro[33], cur[32];
    __shared__ float s1L[128], s2L[128];
    int t = threadIdx.x;
    if (t < 128) { s1L[t] = 0.f; s2L[t] = 0.f; }
    bucket_pass<WRITE_BF16>(blockIdx.x, t, ebuf, bcursor, X, WtL, WtR, bias,
                            outf, outb, Aagg, eL, srcL, cnt, ro, cur, s1L, s2L);
    __syncthreads();
    int slice = blockIdx.x & (NSLICE - 1);
    if (t < 128) {
        atomicAdd(&gstats[slice * 256 + t], s1L[t]);
        atomicAdd(&gstats[slice * 256 + 128 + t], s2L[t]);
    }
}

__global__ void bn_relu_inplace(u16* __restrict__ hb,
                                const float* __restrict__ gstats,
                                const float* __restrict__ gamma,
                                const float* __restrict__ beta,
                                float inv_n, int totalv) {
    __shared__ float ss[256];
    int t = threadIdx.x;
    if (t < 128) {
        float m = 0.f, q = 0.f;
        #pragma unroll
        for (int s = 0; s < NSLICE; ++s) {
            m += gstats[s * 256 + t];
            q += gstats[s * 256 + 128 + t];
        }
        float mean = m * inv_n;
        float var = q * inv_n - mean * mean;
        float inv = 1.0f / sqrtf(var + BN_EPS);
        float sc = gamma[t] * inv;
        ss[t] = sc;
        ss[128 + t] = beta[t] - mean * sc;
    }
    __syncthreads();
    for (int i = blockIdx.x * 256 + t; i < totalv; i += gridDim.x * 256) {
        int cg2 = (i & 15) * 8;
        uint4 p = ((const uint4*)hb)[i];
        float4 scA = *(const float4*)&ss[cg2];
        float4 scB = *(const float4*)&ss[cg2 + 4];
        float4 shA = *(const float4*)&ss[128 + cg2];
        float4 shB = *(const float4*)&ss[128 + cg2 + 4];
        float r0 = fmaxf(fmaf(bflo(p.x), scA.x, shA.x), 0.f);
        float r1 = fmaxf(fmaf(bfhi(p.x), scA.y, shA.y), 0.f);
        float r2 = fmaxf(fmaf(bflo(p.y), scA.z, shA.z), 0.f);
        float r3 = fmaxf(fmaf(bfhi(p.y), scA.w, shA.w), 0.f);
        float r4 = fmaxf(fmaf(bflo(p.z), scB.x, shB.x), 0.f);
        float r5 = fmaxf(fmaf(bfhi(p.z), scB.y, shB.y), 0.f);
        float r6 = fmaxf(fmaf(bflo(p.w), scB.z, shB.z), 0.f);
        float r7 = fmaxf(fmaf(bfhi(p.w), scB.w, shB.w), 0.f);
        uint4 o;
        o.x = pack2(r0, r1);
        o.y = pack2(r2, r3);
        o.z = pack2(r4, r5);
        o.w = pack2(r6, r7);
        ((uint4*)hb)[i] = o;
    }
}

__global__ void bn_apply_kernel(float* __restrict__ h,
                                const float* __restrict__ gstats,
                                const float* __restrict__ gamma,
                                const float* __restrict__ beta,
                                float inv_n, int total4) {
    __shared__ float ss[256];
    int t = threadIdx.x;
    if (t < 128) {
        float m = 0.f, q = 0.f;
        #pragma unroll
        for (int s = 0; s < NSLICE; ++s) {
            m += gstats[s * 256 + t];
            q += gstats[s * 256 + 128 + t];
        }
        float mean = m * inv_n;
        float var = q * inv_n - mean * mean;
        float inv = 1.0f / sqrtf(var + BN_EPS);
        float sc = gamma[t] * inv;
        ss[t] = sc;
        ss[128 + t] = beta[t] - mean * sc;
    }
    __syncthreads();
    for (int i = blockIdx.x * 256 + t; i < total4; i += gridDim.x * 256) {
        int cg2 = i & 31;
        float4 v = ((float4*)h)[i];
        float4 sc = *(const float4*)&ss[cg2 * 4];
        float4 sh = *(const float4*)&ss[128 + cg2 * 4];
        v.x = fmaf(v.x, sc.x, sh.x);
        v.y = fmaf(v.y, sc.y, sh.y);
        v.z = fmaf(v.z, sc.z, sh.z);
        v.w = fmaf(v.w, sc.w, sh.w);
        ((float4*)h)[i] = v;
    }
}

// ---------------------------------------------------------------------------
extern "C" void kernel_launch(void* const* d_in, const int* in_sizes, int n_in,
                              void* d_out, int out_size, void* d_ws, size_t ws_size,
                              hipStream_t stream) {
    const float* x      = (const float*)d_in[0];
    const int*   ei     = (const int*)d_in[1];
    const float* W_l0   = (const float*)d_in[2];
    const float* b_l0   = (const float*)d_in[3];
    const float* W_r0   = (const float*)d_in[4];
    const float* gamma0 = (const float*)d_in[5];
    const float* beta0  = (const float*)d_in[6];
    const float* W_l1   = (const float*)d_in[7];
    const float* b_l1   = (const float*)d_in[8];
    const float* W_r1   = (const float*)d_in[9];
    const float* gamma1 = (const float*)d_in[10];
    const float* beta1  = (const float*)d_in[11];

    const int* src = ei;
    const int* dst = ei + N_EDGES;

    char* w = (char*)d_ws;
    auto alloc = [&](size_t bytes) {
        void* p = (void*)w;
        w += (bytes + 255) & ~(size_t)255;
        return p;
    };
    char* zbase    = w;
    float* gstats0 = (float*)alloc(sizeof(float) * NSLICE * 256);
    float* gstats1 = (float*)alloc(sizeof(float) * NSLICE * 256);
    int* bcursor   = (int*)alloc(sizeof(int) * BUCKS);
    size_t zbytes  = (size_t)(w - zbase);

    uint* ebuf     = (uint*)alloc(sizeof(uint) * (size_t)BUCKS * BSTRIDE);
    u16* xb        = (u16*)alloc(sizeof(u16) * (size_t)NPAD * 128);
    u16* hb        = (u16*)alloc(sizeof(u16) * (size_t)NPAD * 128);
    u16* Wt        = (u16*)alloc(sizeof(u16) * 4 * 16384);
    float* outp    = (float*)d_out;

    hipMemsetAsync(zbase, 0, zbytes, stream);

    float inv_n = 1.0f / (float)N_NODES;
    const int total4 = N_NODES * HID / 4;
    const int totalv = N_NODES * HID / 8;

    scatter_cast<<<SC_BLKS + CAST_BLKS, 1024, 0, stream>>>(
        src, dst, bcursor, ebuf, x, W_l0, W_r0, W_l1, W_r1, xb, Wt);

    void* args[] = {
        (void*)&ebuf, (void*)&bcursor, (void*)&xb, (void*)&hb, (void*)&Wt,
        (void*)&b_l0, (void*)&b_l1,
        (void*)&gamma0, (void*)&beta0, (void*)&gamma1, (void*)&beta1,
        (void*)&outp, (void*)&gstats0, (void*)&gstats1, (void*)&inv_n
    };
    hipError_t cerr = hipLaunchCooperativeKernel((void*)fused_layers,
                                                 dim3(COOP_BLKS), dim3(256),
                                                 args, 0, stream);
    if (cerr != hipSuccess) {
        (void)hipGetLastError();   // clear, take the proven non-coop path
        agg_gemm_nc<1><<<BUCKS, 256, 0, stream>>>(ebuf, bcursor, xb,
            Wt, Wt + 16384, b_l0, nullptr, hb, gstats0);
        bn_relu_inplace<<<1024, 256, 0, stream>>>(hb, gstats0, gamma0, beta0,
                                                  inv_n, totalv);
        agg_gemm_nc<0><<<BUCKS, 256, 0, stream>>>(ebuf, bcursor, hb,
            Wt + 2 * 16384, Wt + 3 * 16384, b_l1, outp, nullptr, gstats1);
        bn_apply_kernel<<<2048, 256, 0, stream>>>(outp, gstats1, gamma1, beta1,
                                                  inv_n, total4);
    }
}